// Round 14
// baseline (144.370 us; speedup 1.0000x reference)
//
#include <hip/hip_runtime.h>
#include <hip/hip_bf16.h>
#include <stdint.h>

#define HID 1024
#define BLKDIM 128
#define BKT 32              // K-tile depth
#define NKT (HID / BKT)     // 32 K-tiles

using short8 = __attribute__((ext_vector_type(8))) short;
using f32x4  = __attribute__((ext_vector_type(4))) float;
using f32x4v = __attribute__((ext_vector_type(4))) float;

__device__ __forceinline__ uint32_t bfround(float f) {
    uint32_t u = __builtin_bit_cast(uint32_t, f);
    return (u + 0x7FFFu + ((u >> 16) & 1u)) >> 16;   // RNE to bf16
}

// ---------------- schedule prepass: expert-grouped pair permutation (r10-12 verified) ----------------
__global__ void build_sched_kernel(const int* __restrict__ cind, int* __restrict__ perm) {
    __shared__ int er[64], srb[64], goff[9];
    const int t = threadIdx.x;
    if (t < 64) er[t] = (cind[t * 32] >> 5) & 7;
    __syncthreads();
    if (t == 0) {
        int cnt[8], off[8];
        for (int e = 0; e < 8; ++e) cnt[e] = 0;
        for (int r = 0; r < 64; ++r) cnt[er[r]]++;
        goff[0] = 0;
        for (int e = 0; e < 8; ++e) { goff[e + 1] = goff[e] + cnt[e]; off[e] = goff[e]; }
        for (int r = 0; r < 64; ++r) srb[off[er[r]]++] = r;
    }
    __syncthreads();
    for (int g = t; g < 1024; g += blockDim.x) {
        int e = 0;
        while (g >= goff[e + 1] * 16) ++e;
        const int ne = goff[e + 1] - goff[e];
        const int local = g - goff[e] * 16;
        const int j = local / ne;
        const int idx = local - j * ne;
        perm[g] = srb[goff[e] + idx] * 16 + j;
    }
}

// ---------------- fused GEMM: 128x256 tile, BK=32, fp32 inputs with in-loop
// bf16 conversion (T14: issue-early/write-late reg staging), expert-grouped perm,
// 48 KB LDS double-buffer, 16x16x32 MFMA, stride-76 epilogue. ----------------
// LDS phys layout (r10-12 verified, 16B slots):
//   phys_slot(row, s) = (s + 4*(row&1)) ^ ((row>>1)&7); addr_ushort = (row>>1)*64 + phys_slot*8
// Staging FORWARD map (fixed this round, cross-validated vs r12's inverse):
//   lane covers (rin = l>>2, q = l&3); superrow = l>>3 = sub;
//   wbase = (l>>3)*64 + (((q + 4*(rin&1)) ^ sub) * 8); straight pack, no swap.
__global__ __launch_bounds__(512, 4)
void sdd_fused_kernel(const float* __restrict__ x, const float* __restrict__ w1,
                      const int* __restrict__ rind, const int* __restrict__ cind,
                      const int* __restrict__ perm,
                      float* __restrict__ out) {
    __shared__ ushort lds[2 * (BLKDIM * BKT + 2 * BLKDIM * BKT)];   // 48 KB

    int g = blockIdx.x;
    const int nwg = gridDim.x;
    if ((nwg & 7) == 0) {                 // bijective XCD swizzle
        const int cpx = nwg >> 3;
        g = (g & 7) * cpx + (g >> 3);
    }
    g = perm[g];                          // expert-grouped work order
    const int k0 = g * 2;
    const int r  = rind[k0];

    const int t = threadIdx.x;
    const int w = t >> 6;                 // wave 0..7
    const int l = t & 63;

    // ---- staging role: lane covers row_in_16 = l>>2, 16B k-slot q = l&3 ----
    const int rin  = l >> 2;
    const int q    = l & 3;
    const int sub  = l >> 3;              // superrow = (rin>>1) = sub (0..7)
    const int wbase = sub * 64 + (((q + 4 * (rin & 1)) ^ sub) * 8);

    const float* agx = x + (size_t)(r * BLKDIM + w * 16 + rin) * HID + q * 8;
    const int cblk = cind[k0 + (w >> 2)];
    const float* bgx0 = w1 + (size_t)(cblk * BLKDIM + (w & 3) * 32 + rin) * HID + q * 8;
    const float* bgx1 = bgx0 + (size_t)16 * HID;

    // ---- compute role: 8 waves as 2(M) x 4(N), each 64x64 (r12-verified) ----
    const int wr   = (w >> 2) * 64;
    const int wcol = (w & 3) * 64;
    const int ps_l = (((l >> 4) + ((l & 1) << 2)) ^ ((l & 15) >> 1)) * 8;
    const int rhalf = (l & 15) >> 1;

    int aoff[4], boff[4];
#pragma unroll
    for (int m = 0; m < 4; ++m) aoff[m] = (wr / 2 + m * 8 + rhalf) * 64 + ps_l;
#pragma unroll
    for (int n = 0; n < 4; ++n) boff[n] = (wcol / 2 + n * 8 + rhalf) * 64 + ps_l;

    f32x4 acc[4][4];
#pragma unroll
    for (int m = 0; m < 4; ++m)
#pragma unroll
        for (int n = 0; n < 4; ++n)
            acc[m][n] = (f32x4){0.f, 0.f, 0.f, 0.f};

    f32x4v ra0, ra1, rb0, rb1, rb2, rb3;   // staging regs (24 VGPR)

    auto issue = [&](int kt) {
        const float* pa  = agx  + kt * BKT;
        const float* pb0 = bgx0 + kt * BKT;
        const float* pb1 = bgx1 + kt * BKT;
        ra0 = *reinterpret_cast<const f32x4v*>(pa);
        ra1 = *reinterpret_cast<const f32x4v*>(pa + 4);
        rb0 = *reinterpret_cast<const f32x4v*>(pb0);
        rb1 = *reinterpret_cast<const f32x4v*>(pb0 + 4);
        rb2 = *reinterpret_cast<const f32x4v*>(pb1);
        rb3 = *reinterpret_cast<const f32x4v*>(pb1 + 4);
    };
    auto pack = [&](f32x4v v0, f32x4v v1) -> uint4 {
        uint4 o;
        o.x = bfround(v0.x) | (bfround(v0.y) << 16);
        o.y = bfround(v0.z) | (bfround(v0.w) << 16);
        o.z = bfround(v1.x) | (bfround(v1.y) << 16);
        o.w = bfround(v1.z) | (bfround(v1.w) << 16);
        return o;
    };
    auto write = [&](int b) {
        ushort* base = lds + b * 12288;
        *reinterpret_cast<uint4*>(&base[w * 512 + wbase])                  = pack(ra0, ra1);
        *reinterpret_cast<uint4*>(&base[4096 + (2 * w) * 512 + wbase])     = pack(rb0, rb1);
        *reinterpret_cast<uint4*>(&base[4096 + (2 * w + 1) * 512 + wbase]) = pack(rb2, rb3);
    };

    // ---- prologue: tile 0 ----
    issue(0);
    asm volatile("s_waitcnt vmcnt(0)" ::: "memory");
    write(0);
    __syncthreads();

    for (int kt = 0; kt < NKT; ++kt) {
        const int cur = kt & 1;
        const bool pre = (kt + 1) < NKT;
        if (pre) issue(kt + 1);           // issue-early: hide HBM under ds_read+MFMA

        const ushort* sa = &lds[cur * 12288];
        const ushort* sb = &lds[cur * 12288 + 4096];
        short8 aF[4], bF[4];
#pragma unroll
        for (int m = 0; m < 4; ++m)
            aF[m] = *reinterpret_cast<const short8*>(&sa[aoff[m]]);
#pragma unroll
        for (int n = 0; n < 4; ++n)
            bF[n] = *reinterpret_cast<const short8*>(&sb[boff[n]]);
        __builtin_amdgcn_s_setprio(1);
#pragma unroll
        for (int m = 0; m < 4; ++m)
#pragma unroll
            for (int n = 0; n < 4; ++n)
                acc[m][n] = __builtin_amdgcn_mfma_f32_16x16x32_bf16(aF[m], bF[n], acc[m][n], 0, 0, 0);
        __builtin_amdgcn_s_setprio(0);

        if (pre) {
            asm volatile("s_waitcnt vmcnt(0)" ::: "memory");   // loads issued at iter start
            write(cur ^ 1);               // write-late into the buffer freed last iter
        }
        __syncthreads();
    }

    // ---- epilogue: per-wave LDS transpose (stride 76), full-line nt float4 stores ----
    const int blk = (w & 3) >> 1;
    float* op = out + (size_t)(k0 + blk) * (BLKDIM * BLKDIM);
    const int colbase = (wcol & 64) ? 64 : 0;
    float* scr = reinterpret_cast<float*>(lds) + w * 1216;   // 16 x 76 floats per wave

#pragma unroll
    for (int m = 0; m < 4; ++m) {
#pragma unroll
        for (int n = 0; n < 4; ++n)
#pragma unroll
            for (int j = 0; j < 4; ++j)
                scr[((l >> 4) * 4 + j) * 76 + n * 16 + (l & 15)] = acc[m][n][j];
#pragma unroll
        for (int rg = 0; rg < 4; ++rg) {
            const int tr = rg * 4 + (l >> 4);
            f32x4 v = *reinterpret_cast<const f32x4*>(&scr[tr * 76 + (l & 15) * 4]);
            __builtin_nontemporal_store(v,
                reinterpret_cast<f32x4*>(&op[(size_t)(wr + m * 16 + tr) * BLKDIM
                                             + colbase + (l & 15) * 4]));
        }
    }
}

// ---------------- fallback (validated round-1 kernel) ----------------
__device__ __forceinline__ void store16f(ushort* dst, float4 v0, float4 v1, float4 v2, float4 v3) {
    uint4 w0, w1;
    w0.x = bfround(v0.x) | (bfround(v0.y) << 16);
    w0.y = bfround(v0.z) | (bfround(v0.w) << 16);
    w0.z = bfround(v1.x) | (bfround(v1.y) << 16);
    w0.w = bfround(v1.z) | (bfround(v1.w) << 16);
    w1.x = bfround(v2.x) | (bfround(v2.y) << 16);
    w1.y = bfround(v2.z) | (bfround(v2.w) << 16);
    w1.z = bfround(v3.x) | (bfround(v3.y) << 16);
    w1.w = bfround(v3.z) | (bfround(v3.w) << 16);
    uint4* d = reinterpret_cast<uint4*>(dst);
    d[0] = w0; d[1] = w1;
}

__global__ __launch_bounds__(256, 2)
void sdd_bf16_kernel(const float* __restrict__ x, const float* __restrict__ w1,
                     const int* __restrict__ rind, const int* __restrict__ cind,
                     float* __restrict__ out) {
    __shared__ ushort sA[2][BLKDIM * 32];
    __shared__ ushort sB[2][BLKDIM * 32];
    const int k = blockIdx.x;
    const int t = threadIdx.x;
    const int r = rind[k];
    const int c = cind[k];
    const float* Abase = x  + (size_t)r * BLKDIM * HID;
    const float* Bbase = w1 + (size_t)c * BLKDIM * HID;
    const int srow = t >> 1, shalf = t & 1;
    const float* aptr = Abase + (size_t)srow * HID + shalf * 16;
    const float* bptr = Bbase + (size_t)srow * HID + shalf * 16;
    const int soff = srow * 32 + shalf * 16;
    const int wv = t >> 6, lane = t & 63;
    const int wr = (wv >> 1) * 64, wc = (wv & 1) * 64;
    const int lr = lane & 15, lk = (lane >> 4) * 8;
    f32x4 acc[4][4];
#pragma unroll
    for (int m = 0; m < 4; ++m)
#pragma unroll
        for (int n = 0; n < 4; ++n) acc[m][n] = (f32x4){0.f, 0.f, 0.f, 0.f};
    float4 ra[4], rb[4];
#pragma unroll
    for (int i = 0; i < 4; ++i) {
        ra[i] = *reinterpret_cast<const float4*>(aptr + i * 4);
        rb[i] = *reinterpret_cast<const float4*>(bptr + i * 4);
    }
    store16f(&sA[0][soff], ra[0], ra[1], ra[2], ra[3]);
    store16f(&sB[0][soff], rb[0], rb[1], rb[2], rb[3]);
    __syncthreads();
    for (int kt = 0; kt < 32; ++kt) {
        const int cur = kt & 1;
        if (kt + 1 < 32) {
            const float* ap = aptr + (kt + 1) * 32;
            const float* bp = bptr + (kt + 1) * 32;
#pragma unroll
            for (int i = 0; i < 4; ++i) {
                ra[i] = *reinterpret_cast<const float4*>(ap + i * 4);
                rb[i] = *reinterpret_cast<const float4*>(bp + i * 4);
            }
        }
        const ushort* sa = sA[cur];
        const ushort* sb = sB[cur];
        short8 aF[4], bF[4];
#pragma unroll
        for (int m = 0; m < 4; ++m) aF[m] = *reinterpret_cast<const short8*>(&sa[(wr + m * 16 + lr) * 32 + lk]);
#pragma unroll
        for (int n = 0; n < 4; ++n) bF[n] = *reinterpret_cast<const short8*>(&sb[(wc + n * 16 + lr) * 32 + lk]);
#pragma unroll
        for (int m = 0; m < 4; ++m)
#pragma unroll
            for (int n = 0; n < 4; ++n)
                acc[m][n] = __builtin_amdgcn_mfma_f32_16x16x32_bf16(aF[m], bF[n], acc[m][n], 0, 0, 0);
        if (kt + 1 < 32) {
            store16f(&sA[cur ^ 1][soff], ra[0], ra[1], ra[2], ra[3]);
            store16f(&sB[cur ^ 1][soff], rb[0], rb[1], rb[2], rb[3]);
        }
        __syncthreads();
    }
    float* op = out + (size_t)k * (BLKDIM * BLKDIM);
    const int rbase = wr + (lane >> 4) * 4;
#pragma unroll
    for (int m = 0; m < 4; ++m)
#pragma unroll
        for (int n = 0; n < 4; ++n) {
            const int col = wc + n * 16 + lr;
#pragma unroll
            for (int j = 0; j < 4; ++j)
                op[(size_t)(rbase + m * 16 + j) * BLKDIM + col] = acc[m][n][j];
        }
}

extern "C" void kernel_launch(void* const* d_in, const int* in_sizes, int n_in,
                              void* d_out, int out_size, void* d_ws, size_t ws_size,
                              hipStream_t stream) {
    const float* x  = (const float*)d_in[0];
    const float* w1 = (const float*)d_in[1];
    const int* ri   = (const int*)d_in[2];
    const int* ci   = (const int*)d_in[3];
    float* out      = (float*)d_out;
    const int nnz   = in_sizes[2];
    const int nx    = in_sizes[0];
    const int nw    = in_sizes[1];

    // Fast path requires the fixed dMoE topology: 64 row-blocks x 32 cols/expert.
    if (ws_size >= 1024 * sizeof(int) && nnz == 2048 && nx == 8388608 && nw == 33554432) {
        int* perm = (int*)d_ws;
        hipLaunchKernelGGL(build_sched_kernel, dim3(1), dim3(256), 0, stream, ci, perm);
        hipLaunchKernelGGL(sdd_fused_kernel, dim3(nnz / 2), dim3(512), 0, stream,
                           x, w1, ri, ci, perm, out);
    } else {
        hipLaunchKernelGGL(sdd_bf16_kernel, dim3(nnz), dim3(256), 0, stream,
                           x, w1, ri, ci, out);
    }
}

// Round 15
// 123.097 us; speedup vs baseline: 1.1728x; 1.1728x over previous
//
#include <hip/hip_runtime.h>
#include <hip/hip_bf16.h>
#include <stdint.h>

#define HID 1024
#define BLKDIM 128
#define BKT 32              // K-tile depth
#define NKT (HID / BKT)     // 32 K-tiles
#define NBUF 3              // triple buffer: depth-2 prefetch

using short8 = __attribute__((ext_vector_type(8))) short;
using f32x4  = __attribute__((ext_vector_type(4))) float;
using f32x4v = __attribute__((ext_vector_type(4))) float;

__device__ __forceinline__ uint32_t bfround(float f) {
    uint32_t u = __builtin_bit_cast(uint32_t, f);
    return (u + 0x7FFFu + ((u >> 16) & 1u)) >> 16;   // RNE to bf16
}

__device__ __forceinline__ void gld16(const ushort* g, const ushort* lds_base) {
    __builtin_amdgcn_global_load_lds(
        (const __attribute__((address_space(1))) void*)g,
        (__attribute__((address_space(3))) void*)lds_base, 16, 0, 0);
}

// ---------------- fused pre-pass: fp32->bf16 cvt + schedule build (r12-verified) ----------------
__global__ __launch_bounds__(256)
void cvt_sched_kernel(const float* __restrict__ x, const float* __restrict__ w1,
                      uint4* __restrict__ xb, uint4* __restrict__ wb,
                      int nx8, int nw8,
                      const int* __restrict__ cind, int* __restrict__ perm) {
    const int t = threadIdx.x;
    if (blockIdx.x == 0) {
        __shared__ int er[64], srb[64], goff[9];
        if (t < 64) er[t] = (cind[t * 32] >> 5) & 7;
        __syncthreads();
        if (t == 0) {
            int cnt[8], off[8];
            for (int e = 0; e < 8; ++e) cnt[e] = 0;
            for (int r = 0; r < 64; ++r) cnt[er[r]]++;
            goff[0] = 0;
            for (int e = 0; e < 8; ++e) { goff[e + 1] = goff[e] + cnt[e]; off[e] = goff[e]; }
            for (int r = 0; r < 64; ++r) srb[off[er[r]]++] = r;
        }
        __syncthreads();
        for (int g = t; g < 1024; g += 256) {
            int e = 0;
            while (g >= goff[e + 1] * 16) ++e;
            const int ne = goff[e + 1] - goff[e];
            const int local = g - goff[e] * 16;
            const int j = local / ne;
            const int idx = local - j * ne;
            perm[g] = srb[goff[e] + idx] * 16 + j;
        }
    }
    const int i = blockIdx.x * 256 + t;
    if (i < nx8) {
        const f32x4v* s = reinterpret_cast<const f32x4v*>(x) + (size_t)i * 2;
        f32x4v v0 = __builtin_nontemporal_load(s);
        f32x4v v1 = __builtin_nontemporal_load(s + 1);
        uint4 w;
        w.x = bfround(v0.x) | (bfround(v0.y) << 16);
        w.y = bfround(v0.z) | (bfround(v0.w) << 16);
        w.z = bfround(v1.x) | (bfround(v1.y) << 16);
        w.w = bfround(v1.z) | (bfround(v1.w) << 16);
        xb[i] = w;
    } else if (i < nx8 + nw8) {
        const int j = i - nx8;
        const f32x4v* s = reinterpret_cast<const f32x4v*>(w1) + (size_t)j * 2;
        f32x4v v0 = __builtin_nontemporal_load(s);
        f32x4v v1 = __builtin_nontemporal_load(s + 1);
        uint4 w;
        w.x = bfround(v0.x) | (bfround(v0.y) << 16);
        w.y = bfround(v0.z) | (bfround(v0.w) << 16);
        w.z = bfround(v1.x) | (bfround(v1.y) << 16);
        w.w = bfround(v1.z) | (bfround(v1.w) << 16);
        wb[j] = w;
    }
}

// ---------------- main GEMM: 128x256 tile, BK=32, counted-vmcnt pipeline,
// 4 waves x (64x128) per-wave tiles (LDS-read-throughput lever: 42.7 FLOP/B vs 32),
// 16x16x32 MFMA, expert-grouped perm, 72 KB LDS, stride-76 epilogue (all r12-verified parts). ----------------
__global__ __launch_bounds__(256, 2)
void sdd_wide_kernel(const ushort* __restrict__ xb, const ushort* __restrict__ wb,
                     const int* __restrict__ rind, const int* __restrict__ cind,
                     const int* __restrict__ perm,
                     float* __restrict__ out) {
    __shared__ ushort lds[NBUF * BLKDIM * BKT + NBUF * 2 * BLKDIM * BKT];  // 72 KB

    int g = blockIdx.x;
    const int nwg = gridDim.x;
    if ((nwg & 7) == 0) {                 // bijective XCD swizzle
        const int cpx = nwg >> 3;
        g = (g & 7) * cpx + (g >> 3);
    }
    g = perm[g];                          // expert-grouped work order
    const int k0 = g * 2;
    const int r  = rind[k0];

    const int t = threadIdx.x;
    const int w = t >> 6;                 // wave 0..3
    const int l = t & 63;

    ushort* sAb = lds;                            // NBUF x 4096 ushorts
    ushort* sBb = lds + NBUF * BLKDIM * BKT;      // NBUF x 8192 ushorts

    // ---- staging role (r12-verified inverse map): lane -> (row_in_16, slot4) ----
    const int unx   = (l & 7) ^ ((l >> 3) & 7);
    const int rin16 = 2 * (l >> 3) + (unx >> 2);
    const int kofs  = (unx & 3) * 8;

    // wave w stages A rows w*32..w*32+31 (2 issues) and B panel rows w*64..w*64+63 (4 issues)
    const ushort* agb = xb + (size_t)(r * BLKDIM + w * 32 + rin16) * HID + kofs;
    const int cblk = cind[k0 + (w >> 1)];
    const ushort* bgb = wb + (size_t)(cblk * BLKDIM + (w & 1) * 64 + rin16) * HID + kofs;

    // ---- compute role: 4 waves as 2(M) x 2(blocks), each 64x128 ----
    const int wr   = (w >> 1) * 64;
    const int wblk = w & 1;               // which output block (B half)
    const int ps_l = (((l >> 4) + ((l & 1) << 2)) ^ ((l & 15) >> 1)) * 8;
    const int rhalf = (l & 15) >> 1;

    int aoff[4], boff[8];
#pragma unroll
    for (int m = 0; m < 4; ++m) aoff[m] = ((w >> 1) * 32 + m * 8 + rhalf) * 64 + ps_l;
#pragma unroll
    for (int n = 0; n < 8; ++n) boff[n] = (wblk * 64 + n * 8 + rhalf) * 64 + ps_l;

    f32x4 acc[4][8];
#pragma unroll
    for (int m = 0; m < 4; ++m)
#pragma unroll
        for (int n = 0; n < 8; ++n)
            acc[m][n] = (f32x4){0.f, 0.f, 0.f, 0.f};

    auto stage = [&](int b, int kt) {
        gld16(agb + kt * BKT,                          &sAb[b * 4096 + w * 1024]);
        gld16(agb + (size_t)16 * HID + kt * BKT,       &sAb[b * 4096 + w * 1024 + 512]);
        gld16(bgb + kt * BKT,                          &sBb[b * 8192 + w * 2048]);
        gld16(bgb + (size_t)16 * HID + kt * BKT,       &sBb[b * 8192 + w * 2048 + 512]);
        gld16(bgb + (size_t)32 * HID + kt * BKT,       &sBb[b * 8192 + w * 2048 + 1024]);
        gld16(bgb + (size_t)48 * HID + kt * BKT,       &sBb[b * 8192 + w * 2048 + 1536]);
    };

    stage(0, 0);
    stage(1, 1);
    asm volatile("s_waitcnt vmcnt(6)" ::: "memory");   // tile 0 resident
    __builtin_amdgcn_s_barrier();
    __builtin_amdgcn_sched_barrier(0);

    for (int kt = 0; kt < NKT; ++kt) {
        const int cur = kt % 3;
        const int nxt = (kt + 2) % 3;
        const bool pre = (kt + 2) < NKT;
        const ushort* sa = &sAb[cur * 4096];
        const ushort* sb = &sBb[cur * 8192];

        short8 aF[4], bF[8];
#pragma unroll
        for (int m = 0; m < 4; ++m)
            aF[m] = *reinterpret_cast<const short8*>(&sa[aoff[m]]);
#pragma unroll
        for (int n = 0; n < 8; ++n)
            bF[n] = *reinterpret_cast<const short8*>(&sb[boff[n]]);
        if (pre) stage(nxt, kt + 2);
        __builtin_amdgcn_s_setprio(1);
#pragma unroll
        for (int m = 0; m < 4; ++m)
#pragma unroll
            for (int n = 0; n < 8; ++n)
                acc[m][n] = __builtin_amdgcn_mfma_f32_16x16x32_bf16(aF[m], bF[n], acc[m][n], 0, 0, 0);
        __builtin_amdgcn_s_setprio(0);

        if (pre) asm volatile("s_waitcnt vmcnt(6)" ::: "memory");
        else     asm volatile("s_waitcnt vmcnt(0)" ::: "memory");
        __builtin_amdgcn_s_barrier();
        __builtin_amdgcn_sched_barrier(0);
    }

    // ---- epilogue: per-wave LDS transpose (stride 76, r12-verified), run per 64-col half ----
    float* op = out + (size_t)(k0 + wblk) * (BLKDIM * BLKDIM);
    float* scr = reinterpret_cast<float*>(lds) + w * 1216;   // 16 x 76 floats per wave

#pragma unroll
    for (int m = 0; m < 4; ++m)
#pragma unroll
        for (int h = 0; h < 2; ++h) {
#pragma unroll
            for (int n = 0; n < 4; ++n)
#pragma unroll
                for (int j = 0; j < 4; ++j)
                    scr[((l >> 4) * 4 + j) * 76 + n * 16 + (l & 15)] = acc[m][h * 4 + n][j];
#pragma unroll
            for (int rg = 0; rg < 4; ++rg) {
                const int tr = rg * 4 + (l >> 4);
                f32x4 v = *reinterpret_cast<const f32x4*>(&scr[tr * 76 + (l & 15) * 4]);
                __builtin_nontemporal_store(v,
                    reinterpret_cast<f32x4*>(&op[(size_t)(wr + m * 16 + tr) * BLKDIM
                                                 + h * 64 + (l & 15) * 4]));
            }
        }
}

// ---------------- fallback (validated round-1 kernel) ----------------
__device__ __forceinline__ void store16f(ushort* dst, float4 v0, float4 v1, float4 v2, float4 v3) {
    uint4 w0, w1;
    w0.x = bfround(v0.x) | (bfround(v0.y) << 16);
    w0.y = bfround(v0.z) | (bfround(v0.w) << 16);
    w0.z = bfround(v1.x) | (bfround(v1.y) << 16);
    w0.w = bfround(v1.z) | (bfround(v1.w) << 16);
    w1.x = bfround(v2.x) | (bfround(v2.y) << 16);
    w1.y = bfround(v2.z) | (bfround(v2.w) << 16);
    w1.z = bfround(v3.x) | (bfround(v3.y) << 16);
    w1.w = bfround(v3.z) | (bfround(v3.w) << 16);
    uint4* d = reinterpret_cast<uint4*>(dst);
    d[0] = w0; d[1] = w1;
}

__global__ __launch_bounds__(256, 2)
void sdd_bf16_kernel(const float* __restrict__ x, const float* __restrict__ w1,
                     const int* __restrict__ rind, const int* __restrict__ cind,
                     float* __restrict__ out) {
    __shared__ ushort sA[2][BLKDIM * 32];
    __shared__ ushort sB[2][BLKDIM * 32];
    const int k = blockIdx.x;
    const int t = threadIdx.x;
    const int r = rind[k];
    const int c = cind[k];
    const float* Abase = x  + (size_t)r * BLKDIM * HID;
    const float* Bbase = w1 + (size_t)c * BLKDIM * HID;
    const int srow = t >> 1, shalf = t & 1;
    const float* aptr = Abase + (size_t)srow * HID + shalf * 16;
    const float* bptr = Bbase + (size_t)srow * HID + shalf * 16;
    const int soff = srow * 32 + shalf * 16;
    const int wv = t >> 6, lane = t & 63;
    const int wr = (wv >> 1) * 64, wc = (wv & 1) * 64;
    const int lr = lane & 15, lk = (lane >> 4) * 8;
    f32x4 acc[4][4];
#pragma unroll
    for (int m = 0; m < 4; ++m)
#pragma unroll
        for (int n = 0; n < 4; ++n) acc[m][n] = (f32x4){0.f, 0.f, 0.f, 0.f};
    float4 ra[4], rb[4];
#pragma unroll
    for (int i = 0; i < 4; ++i) {
        ra[i] = *reinterpret_cast<const float4*>(aptr + i * 4);
        rb[i] = *reinterpret_cast<const float4*>(bptr + i * 4);
    }
    store16f(&sA[0][soff], ra[0], ra[1], ra[2], ra[3]);
    store16f(&sB[0][soff], rb[0], rb[1], rb[2], rb[3]);
    __syncthreads();
    for (int kt = 0; kt < 32; ++kt) {
        const int cur = kt & 1;
        if (kt + 1 < 32) {
            const float* ap = aptr + (kt + 1) * 32;
            const float* bp = bptr + (kt + 1) * 32;
#pragma unroll
            for (int i = 0; i < 4; ++i) {
                ra[i] = *reinterpret_cast<const float4*>(ap + i * 4);
                rb[i] = *reinterpret_cast<const float4*>(bp + i * 4);
            }
        }
        const ushort* sa = sA[cur];
        const ushort* sb = sB[cur];
        short8 aF[4], bF[4];
#pragma unroll
        for (int m = 0; m < 4; ++m) aF[m] = *reinterpret_cast<const short8*>(&sa[(wr + m * 16 + lr) * 32 + lk]);
#pragma unroll
        for (int n = 0; n < 4; ++n) bF[n] = *reinterpret_cast<const short8*>(&sb[(wc + n * 16 + lr) * 32 + lk]);
#pragma unroll
        for (int m = 0; m < 4; ++m)
#pragma unroll
            for (int n = 0; n < 4; ++n)
                acc[m][n] = __builtin_amdgcn_mfma_f32_16x16x32_bf16(aF[m], bF[n], acc[m][n], 0, 0, 0);
        if (kt + 1 < 32) {
            store16f(&sA[cur ^ 1][soff], ra[0], ra[1], ra[2], ra[3]);
            store16f(&sB[cur ^ 1][soff], rb[0], rb[1], rb[2], rb[3]);
        }
        __syncthreads();
    }
    float* op = out + (size_t)k * (BLKDIM * BLKDIM);
    const int rbase = wr + (lane >> 4) * 4;
#pragma unroll
    for (int m = 0; m < 4; ++m)
#pragma unroll
        for (int n = 0; n < 4; ++n) {
            const int col = wc + n * 16 + lr;
#pragma unroll
            for (int j = 0; j < 4; ++j)
                op[(size_t)(rbase + m * 16 + j) * BLKDIM + col] = acc[m][n][j];
        }
}

extern "C" void kernel_launch(void* const* d_in, const int* in_sizes, int n_in,
                              void* d_out, int out_size, void* d_ws, size_t ws_size,
                              hipStream_t stream) {
    const float* x  = (const float*)d_in[0];
    const float* w1 = (const float*)d_in[1];
    const int* ri   = (const int*)d_in[2];
    const int* ci   = (const int*)d_in[3];
    float* out      = (float*)d_out;
    const int nnz   = in_sizes[2];
    const int nx    = in_sizes[0];
    const int nw    = in_sizes[1];

    const size_t need = ((size_t)nx + (size_t)nw) * sizeof(ushort) + 4096 * sizeof(int);
    // Fast path requires the fixed dMoE topology: 64 row-blocks x 32 cols/expert.
    if (ws_size >= need && nnz == 2048 && nx == 8388608 && nw == 33554432) {
        ushort* xb = (ushort*)d_ws;
        ushort* wb = xb + nx;
        int* perm  = (int*)(wb + nw);
        const int nx8 = nx / 8, nw8 = nw / 8;
        const int ncvt = (nx8 + nw8 + 255) / 256;
        hipLaunchKernelGGL(cvt_sched_kernel, dim3(ncvt), dim3(256), 0, stream,
                           x, w1, (uint4*)xb, (uint4*)wb, nx8, nw8, ci, perm);
        hipLaunchKernelGGL(sdd_wide_kernel, dim3(nnz / 2), dim3(256), 0, stream,
                           xb, wb, ri, ci, perm, out);
    } else {
        hipLaunchKernelGGL(sdd_bf16_kernel, dim3(nnz), dim3(256), 0, stream,
                           x, w1, ri, ci, out);
    }
}